// Round 1
// baseline (1009.592 us; speedup 1.0000x reference)
//
#include <hip/hip_runtime.h>

typedef __attribute__((ext_vector_type(8))) short short8;
typedef __attribute__((ext_vector_type(4))) float f32x4;

#define EPSV 1e-6f

__device__ __forceinline__ unsigned short f2bf(float f){
  unsigned int u = __float_as_uint(f);
  u = u + 0x7fffu + ((u >> 16) & 1u);
  return (unsigned short)(u >> 16);
}
__device__ __forceinline__ float bf2f(unsigned short h){
  return __uint_as_float(((unsigned int)h) << 16);
}

// ---- LDS layout (bytes) ----
#define AXN_OFF 0          // 32768: bf16 A_xn [32 rows][512 k], 1KB row, 16B-XOR swizzled
#define AHM_OFF 32768      // 32768: bf16 A_hm  (AXN+AHM reused as fp32 out-stage [512][32])
#define RAW_OFF 65536      // 36864: bf16 raw tile [512][36]
#define PART_OFF 102400    // 2112 : partial-reduce scratch
#define INVX_OFF 104512    // 128
#define INVH_OFF 104640    // 144 (34 used)
#define SSQ2_OFF 104784    // 1152: [32 m][9] per-wave ssq partials
#define INVO_OFF 105936    // 128
#define SMEM_BYTES 106112

extern "C" __global__ void wconv_kernel(const float* __restrict__ xW, const float* __restrict__ hW,
                                        unsigned short* __restrict__ xWb, unsigned short* __restrict__ hWb){
  int i = blockIdx.x*256 + threadIdx.x;   // grid covers 1536*512 = 786432
  xWb[i] = f2bf(xW[i]);
  hWb[i] = f2bf(hW[i]);
}

extern "C" __global__ void __launch_bounds__(512, 2)
gru_fused(const float* __restrict__ x, const float* __restrict__ h,
          const float* __restrict__ inw, const float* __restrict__ hidw,
          const float* __restrict__ outw,
          const float* __restrict__ xb, const float* __restrict__ hmixWc,
          const float* __restrict__ hmixb, const float* __restrict__ hb,
          const unsigned short* __restrict__ xWb, const unsigned short* __restrict__ hWb,
          float* __restrict__ out)
{
  extern __shared__ __align__(16) char smem[];
  const int b  = blockIdx.y;
  const int f0 = blockIdx.x * 32;
  const int t  = threadIdx.x;

  unsigned short* raw = (unsigned short*)(smem + RAW_OFF);
  float* part = (float*)(smem + PART_OFF);

  // ================= stage x tile (bf16) : raw[c][0..31] =================
  {
    const int fq = t & 7, cb = t >> 3;
    #pragma unroll
    for (int pass = 0; pass < 8; ++pass){
      int c = pass*64 + cb;
      f32x4 v = *(const f32x4*)(x + ((size_t)(b*512 + c))*1024 + f0 + fq*4);
      unsigned short* d = raw + c*36 + fq*4;
      d[0] = f2bf(v[0]); d[1] = f2bf(v[1]); d[2] = f2bf(v[2]); d[3] = f2bf(v[3]);
    }
  }
  __syncthreads();
  // ssq over channels per f (x)
  {
    const int f = t & 31, cs = t >> 5;       // 16 groups of 32 channels
    float p = 0.f;
    for (int i = 0; i < 32; ++i){
      float v = bf2f(raw[(cs*32 + i)*36 + f]);
      p += v*v;
    }
    part[cs*33 + f] = p;
  }
  __syncthreads();
  if (t < 32){
    float s = 0.f;
    for (int i = 0; i < 16; ++i) s += part[i*33 + t];
    ((float*)(smem + INVX_OFF))[t] = rsqrtf(s*(1.f/512.f) + EPSV);
  }
  __syncthreads();
  // build A_xn[f][c] = x*inv*inw  (bf16, swizzled rows)
  {
    const int f = t >> 4, cc = t & 15;
    const float iv = ((float*)(smem + INVX_OFF))[f];
    #pragma unroll
    for (int it = 0; it < 4; ++it){
      int c0 = (cc + it*16)*8;
      short8 pk;
      #pragma unroll
      for (int j = 0; j < 8; ++j){
        float v = bf2f(raw[(c0+j)*36 + f]) * iv * inw[c0+j];
        pk[j] = (short)f2bf(v);
      }
      *(short8*)(smem + AXN_OFF + f*1024 + ((c0*2) ^ ((f&7)<<4))) = pk;
    }
  }
  __syncthreads();

  // ================= stage h tile: cols 1..32 main, 0 & 33 halo =================
  {
    const int fq = t & 7, cb = t >> 3;
    #pragma unroll
    for (int pass = 0; pass < 8; ++pass){
      int c = pass*64 + cb;
      f32x4 v = *(const f32x4*)(h + ((size_t)(b*512 + c))*1024 + f0 + fq*4);
      unsigned short* d = raw + c*36 + 1 + fq*4;
      d[0] = f2bf(v[0]); d[1] = f2bf(v[1]); d[2] = f2bf(v[2]); d[3] = f2bf(v[3]);
    }
    {
      int c = t;
      size_t base = ((size_t)(b*512 + c))*1024;
      float lv = (f0 > 0)          ? h[base + f0 - 1]  : 0.f;
      float rv = (f0 + 32 < 1024)  ? h[base + f0 + 32] : 0.f;
      raw[c*36 + 0]  = f2bf(lv);
      raw[c*36 + 33] = f2bf(rv);
    }
  }
  __syncthreads();
  // ssq over channels per f (h, 34 cols incl. halo)
  {
    const int fw = t & 63, cs = t >> 6;      // 8 groups of 64 channels
    if (fw < 34){
      float p = 0.f;
      for (int i = 0; i < 64; ++i){
        float v = bf2f(raw[(cs*64 + i)*36 + fw]);
        p += v*v;
      }
      part[cs*35 + fw] = p;
    }
  }
  __syncthreads();
  if (t < 34){
    float s = 0.f;
    for (int i = 0; i < 8; ++i) s += part[i*35 + t];
    ((float*)(smem + INVH_OFF))[t] = rsqrtf(s*(1.f/512.f) + EPSV);
  }
  __syncthreads();
  // build A_hm[f][c] = depthwise-band(rmsnorm(h)) + hmixb   (bf16, swizzled)
  {
    const int f = t >> 4, cc = t & 15;
    const float* invh = (const float*)(smem + INVH_OFF);
    const float iL = invh[f], iC = invh[f+1], iR = invh[f+2];
    #pragma unroll
    for (int it = 0; it < 4; ++it){
      int c0 = (cc + it*16)*8;
      short8 pk;
      #pragma unroll
      for (int j = 0; j < 8; ++j){
        int c = c0 + j;
        float hL = bf2f(raw[c*36 + f])     * iL;
        float hC = bf2f(raw[c*36 + f + 1]) * iC;
        float hR = bf2f(raw[c*36 + f + 2]) * iR;
        float v = (hmixWc[c*3]*hL + hmixWc[c*3+1]*hC + hmixWc[c*3+2]*hR) * hidw[c] + hmixb[c];
        pk[j] = (short)f2bf(v);
      }
      *(short8*)(smem + AHM_OFF + f*1024 + ((c0*2) ^ ((f&7)<<4))) = pk;
    }
  }
  __syncthreads();

  // ================= GEMM: 6 gate-matmuls, r/z accumulate across both sources =================
  const int wv = t >> 6, lane = t & 63, li = lane & 15, lg = lane >> 4;
  const int n0 = wv*64;
  f32x4 ar[2][4] = {}, az[2][4] = {}, axg[2][4] = {}, ahg[2][4] = {};
  #pragma unroll
  for (int src = 0; src < 2; ++src){
    const char* A = smem + (src ? AHM_OFF : AXN_OFF);
    const unsigned short* W = src ? hWb : xWb;
    for (int k0 = 0; k0 < 512; k0 += 32){
      const int kb = (k0*2 + lg*16) ^ ((li & 7) << 4);
      short8 a0 = *(const short8*)(A + li*1024 + kb);
      short8 a1 = *(const short8*)(A + (li+16)*1024 + kb);
      #pragma unroll
      for (int nt = 0; nt < 4; ++nt){
        const unsigned short* bp = W + (size_t)(n0 + nt*16 + li)*512 + k0 + lg*8;
        short8 br = *(const short8*)(bp);
        short8 bz = *(const short8*)(bp + 512*512);
        short8 bg = *(const short8*)(bp + 1024*512);
        ar[0][nt] = __builtin_amdgcn_mfma_f32_16x16x32_bf16(a0, br, ar[0][nt], 0,0,0);
        ar[1][nt] = __builtin_amdgcn_mfma_f32_16x16x32_bf16(a1, br, ar[1][nt], 0,0,0);
        az[0][nt] = __builtin_amdgcn_mfma_f32_16x16x32_bf16(a0, bz, az[0][nt], 0,0,0);
        az[1][nt] = __builtin_amdgcn_mfma_f32_16x16x32_bf16(a1, bz, az[1][nt], 0,0,0);
        if (src == 0){
          axg[0][nt] = __builtin_amdgcn_mfma_f32_16x16x32_bf16(a0, bg, axg[0][nt], 0,0,0);
          axg[1][nt] = __builtin_amdgcn_mfma_f32_16x16x32_bf16(a1, bg, axg[1][nt], 0,0,0);
        } else {
          ahg[0][nt] = __builtin_amdgcn_mfma_f32_16x16x32_bf16(a0, bg, ahg[0][nt], 0,0,0);
          ahg[1][nt] = __builtin_amdgcn_mfma_f32_16x16x32_bf16(a1, bg, ahg[1][nt], 0,0,0);
        }
      }
    }
  }

  // ================= gates + h_new + s = h_new + x_t (registers) =================
  float ps[8] = {0,0,0,0,0,0,0,0};
  #pragma unroll
  for (int nt = 0; nt < 4; ++nt){
    const int c = n0 + nt*16 + li;
    const float xbr = xb[c], xbz = xb[512+c], xbg = xb[1024+c];
    const float hbr = hb[c], hbz = hb[512+c], hbg = hb[1024+c];
    #pragma unroll
    for (int mt = 0; mt < 2; ++mt){
      const size_t idx = ((size_t)(b*512 + c))*1024 + f0 + mt*16 + lg*4;
      const f32x4 hp = *(const f32x4*)(h + idx);
      const f32x4 xt = *(const f32x4*)(x + idx);
      f32x4 sv;
      #pragma unroll
      for (int j = 0; j < 4; ++j){
        float rr = 1.f/(1.f + __expf(-(ar[mt][nt][j] + xbr + hbr)));
        float zz = 1.f/(1.f + __expf(-(az[mt][nt][j] + xbz + hbz)));
        float g  = axg[mt][nt][j] + xbg + rr*(ahg[mt][nt][j] + hbg);
        float e  = __expf(-2.f*fabsf(g));
        float th = (1.f - e)/(1.f + e);
        th = copysignf(th, g);
        float hv = (1.f - zz)*th + zz*hp[j];
        float s  = hv + xt[j];
        sv[j] = s;
        ps[mt*4 + j] += s*s;
      }
      ar[mt][nt] = sv;   // reuse accumulator registers for s
    }
  }
  // reduce s^2 across the 16 lanes sharing each pixel row
  #pragma unroll
  for (int off = 1; off < 16; off <<= 1){
    #pragma unroll
    for (int p = 0; p < 8; ++p) ps[p] += __shfl_xor(ps[p], off);
  }
  __syncthreads();   // all waves done reading A tiles; safe to reuse as out-stage

  // stage s into swizzled fp32 [512][32] (reusing A region)
  float* stg = (float*)(smem + AXN_OFF);
  #pragma unroll
  for (int nt = 0; nt < 4; ++nt){
    const int n = n0 + nt*16 + li;
    #pragma unroll
    for (int mt = 0; mt < 2; ++mt){
      const int m0 = mt*16 + lg*4;
      *(f32x4*)(stg + n*32 + (m0 ^ ((n & 7) << 2))) = ar[mt][nt];
    }
  }
  // deterministic cross-wave ssq reduce
  float* sq2 = (float*)(smem + SSQ2_OFF); // [32 m][9]
  if (li == 0){
    #pragma unroll
    for (int p = 0; p < 8; ++p){
      int m = (p >> 2)*16 + lg*4 + (p & 3);
      sq2[m*9 + wv] = ps[p];
    }
  }
  __syncthreads();
  if (t < 32){
    float s = 0.f;
    for (int i = 0; i < 8; ++i) s += sq2[t*9 + i];
    ((float*)(smem + INVO_OFF))[t] = rsqrtf(s*(1.f/512.f) + EPSV);
  }
  __syncthreads();
  // out-rmsnorm scale + coalesced write
  {
    const float* invO = (const float*)(smem + INVO_OFF);
    const int cb = t >> 3, ch = t & 7;
    #pragma unroll
    for (int pass = 0; pass < 8; ++pass){
      int c = pass*64 + cb;
      int base = (ch*4) ^ ((c & 7) << 2);
      f32x4 v = *(const f32x4*)(stg + c*32 + base);
      float ow = outw[c];
      f32x4 o;
      #pragma unroll
      for (int j = 0; j < 4; ++j) o[j] = v[j] * invO[ch*4 + j] * ow;
      *(f32x4*)(out + ((size_t)(b*512 + c))*1024 + f0 + ch*4) = o;
    }
  }
}

extern "C" void kernel_launch(void* const* d_in, const int* in_sizes, int n_in,
                              void* d_out, int out_size, void* d_ws, size_t ws_size,
                              hipStream_t stream){
  (void)in_sizes; (void)n_in; (void)out_size; (void)ws_size;
  const float* x      = (const float*)d_in[0];
  const float* h      = (const float*)d_in[1];
  const float* inw    = (const float*)d_in[2];
  const float* hidw   = (const float*)d_in[3];
  const float* outw   = (const float*)d_in[4];
  const float* xW     = (const float*)d_in[5];
  const float* xb     = (const float*)d_in[6];
  const float* hmixW  = (const float*)d_in[7];
  const float* hmixb  = (const float*)d_in[8];
  const float* hW     = (const float*)d_in[9];
  const float* hb     = (const float*)d_in[10];

  unsigned short* xWb = (unsigned short*)d_ws;
  unsigned short* hWb = xWb + 786432;          // 1536*512

  static bool attr_set_ok = []{ return true; }();
  (void)attr_set_ok;
  hipFuncSetAttribute(reinterpret_cast<const void*>(gru_fused),
                      hipFuncAttributeMaxDynamicSharedMemorySize, SMEM_BYTES);

  wconv_kernel<<<3072, 256, 0, stream>>>(xW, hW, xWb, hWb);
  dim3 grid(32, 64);   // (F/32 pixel tiles, B)
  gru_fused<<<grid, 512, SMEM_BYTES, stream>>>(x, h, inw, hidw, outw,
                                               xb, hmixW, hmixb, hb,
                                               xWb, hWb, (float*)d_out);
}